// Round 4
// baseline (97.377 us; speedup 1.0000x reference)
//
#include <hip/hip_runtime.h>

namespace {

constexpr int Cn   = 256;          // channels
constexpr int Hh   = 128;
constexpr int Ww   = 128;
constexpr int TILE = 16;           // spatial tile edge
constexpr int CCH  = 8;            // channels per LDS chunk
constexpr int NCH  = Cn / CCH;     // 32 chunks
constexpr int X2T  = 24;           // x2 tile edge (TILE + 2*4)
constexpr int X2N  = X2T * X2T;    // 576 floats per channel
constexpr int X1N  = TILE * TILE;  // 256 floats per channel
constexpr int NOFF = 81;
constexpr int NLOC = 21;           // offsets per wave (1 overlap at seams)

// wave WV handles window rows di = 2*WV + r (r=0..2); dj ranges per row:
constexpr int DJLO[4][3]  = {{0,0,0},{2,0,0},{4,0,0},{6,0,0}};
constexpr int DJHI[4][3]  = {{8,8,2},{8,8,4},{8,8,6},{8,8,8}};
constexpr int LBASE[4][3] = {{0,9,18},{0,7,16},{0,5,14},{0,3,12}};

template<int WV, int R>
__device__ __forceinline__ void compute_row(const float4 a,
                                            const float* __restrict__ bp,
                                            float acc[NLOC][4])
{
  float win[12];
  *reinterpret_cast<float4*>(win)     = *reinterpret_cast<const float4*>(bp);
  *reinterpret_cast<float4*>(win + 4) = *reinterpret_cast<const float4*>(bp + 4);
  *reinterpret_cast<float4*>(win + 8) = *reinterpret_cast<const float4*>(bp + 8);
  constexpr int lo = DJLO[WV][R];
  constexpr int hi = DJHI[WV][R];
  constexpr int lb = LBASE[WV][R];
#pragma unroll
  for (int dj = lo; dj <= hi; ++dj) {
    const int li = lb + (dj - lo);
    acc[li][0] = fmaf(a.x, win[dj + 0], acc[li][0]);
    acc[li][1] = fmaf(a.y, win[dj + 1], acc[li][1]);
    acc[li][2] = fmaf(a.z, win[dj + 2], acc[li][2]);
    acc[li][3] = fmaf(a.w, win[dj + 3], acc[li][3]);
  }
}

template<int WV>
__device__ __forceinline__ void compute_chunk(const float* __restrict__ x1s,
                                              const float* __restrict__ x2s,
                                              int hoff1, int hoff2,
                                              float acc[NLOC][4])
{
#pragma unroll
  for (int cc = 0; cc < CCH; ++cc) {
    const float4 a = *reinterpret_cast<const float4*>(x1s + cc * X1N + hoff1);
    const float* bp = x2s + cc * X2N + hoff2;
    compute_row<WV, 0>(a, bp + (2 * WV + 0) * X2T, acc);
    compute_row<WV, 1>(a, bp + (2 * WV + 1) * X2T, acc);
    compute_row<WV, 2>(a, bp + (2 * WV + 2) * X2T, acc);
  }
}

__global__ __launch_bounds__(256, 1)
void costvol_kernel(const float* __restrict__ x1,
                    const float* __restrict__ x2,
                    float* __restrict__ out)
{
  __shared__ float s1[2][CCH * X1N];   // x1 tiles, 16 KB
  __shared__ float s2[2][CCH * X2N];   // x2 tiles (haloed), 36.9 KB

  const int t    = threadIdx.x;
  const int wid  = t >> 6;
  const int lane = t & 63;
  const int h    = lane >> 2;        // 0..15 tile row
  const int m    = lane & 3;         // pixel group: cols 4m..4m+3

  const int tx = blockIdx.x, ty = blockIdx.y, b = blockIdx.z;
  const int x0 = tx * TILE, y0 = ty * TILE;

  // ---- staging address precompute ----
  // x1: thread stages element t of the 16x16 tile
  const int r1 = t >> 4, c1 = t & 15;
  const float* g1 = x1 + ((size_t)(b * Cn) * Hh + (y0 + r1)) * Ww + (x0 + c1);
  // x2: thread stages elements t, t+256, t+512 (last only for t<64) of 24x24
  const float* g2 = x2 + (size_t)(b * Cn) * (Hh * Ww);
  int  off2[3];
  bool v2[3];
#pragma unroll
  for (int j = 0; j < 3; ++j) {
    const int e   = t + 256 * j;
    const int row = e / X2T, col = e % X2T;
    const int gy = y0 - 4 + row, gx = x0 - 4 + col;
    const bool ok = (e < X2N) && (gy >= 0) && (gy < Hh) && (gx >= 0) && (gx < Ww);
    v2[j]   = ok;
    off2[j] = ok ? (gy * Ww + gx) : 0;
  }

  float rx1[CCH];
  float rx2[CCH][3];

  auto stage_load = [&](int k) {
    const int c0 = k * CCH;
#pragma unroll
    for (int cc = 0; cc < CCH; ++cc) {
      const size_t cb = (size_t)(c0 + cc) * (Hh * Ww);
      rx1[cc] = g1[cb];
#pragma unroll
      for (int j = 0; j < 3; ++j)
        rx2[cc][j] = v2[j] ? g2[cb + off2[j]] : 0.0f;
    }
  };
  auto stage_write = [&](int nb) {
#pragma unroll
    for (int cc = 0; cc < CCH; ++cc) {
      s1[nb][cc * X1N + t] = rx1[cc];
      s2[nb][cc * X2N + t]       = rx2[cc][0];
      s2[nb][cc * X2N + t + 256] = rx2[cc][1];
      if (t < X2N - 512) s2[nb][cc * X2N + t + 512] = rx2[cc][2];
    }
  };

  float acc[NLOC][4];
#pragma unroll
  for (int i = 0; i < NLOC; ++i)
#pragma unroll
    for (int p = 0; p < 4; ++p) acc[i][p] = 0.0f;

  const int hoff1 = h * TILE + 4 * m;
  const int hoff2 = h * X2T  + 4 * m;

  stage_load(0);
  stage_write(0);
  __syncthreads();

  for (int k = 0; k < NCH; ++k) {
    if (k + 1 < NCH) stage_load(k + 1);          // issue early (T14)
    const float* p1 = s1[k & 1];
    const float* p2 = s2[k & 1];
    switch (wid) {
      case 0:  compute_chunk<0>(p1, p2, hoff1, hoff2, acc); break;
      case 1:  compute_chunk<1>(p1, p2, hoff1, hoff2, acc); break;
      case 2:  compute_chunk<2>(p1, p2, hoff1, hoff2, acc); break;
      default: compute_chunk<3>(p1, p2, hoff1, hoff2, acc); break;
    }
    if (k + 1 < NCH) stage_write((k + 1) & 1);   // write late
    __syncthreads();
  }

  // ---- epilogue: scale by 1/C and store (some seam offsets stored twice
  // by two waves with identical values — benign) ----
  const float invc = 1.0f / (float)Cn;
  const int y  = y0 + h;
  const int xb = x0 + 4 * m;
#pragma unroll
  for (int li = 0; li < NLOC; ++li) {
    const int o = 20 * wid + li;
    float4 v;
    v.x = acc[li][0] * invc;
    v.y = acc[li][1] * invc;
    v.z = acc[li][2] * invc;
    v.w = acc[li][3] * invc;
    *reinterpret_cast<float4*>(out + (((size_t)b * NOFF + o) * Hh + y) * Ww + xb) = v;
  }
}

} // namespace

extern "C" void kernel_launch(void* const* d_in, const int* in_sizes, int n_in,
                              void* d_out, int out_size, void* d_ws, size_t ws_size,
                              hipStream_t stream) {
  const float* x1 = (const float*)d_in[0];
  const float* x2 = (const float*)d_in[1];
  float* out = (float*)d_out;

  dim3 grid(Ww / TILE, Hh / TILE, 4);   // 8 x 8 x 4 = 256 blocks
  dim3 block(256);
  costvol_kernel<<<grid, block, 0, stream>>>(x1, x2, out);
}

// Round 5
// 76.857 us; speedup vs baseline: 1.2670x; 1.2670x over previous
//
#include <hip/hip_runtime.h>

namespace {

constexpr int Cn   = 256;            // channels
constexpr int Hh   = 128;
constexpr int Ww   = 128;
constexpr int HW   = Hh * Ww;
constexpr int TILE = 16;             // spatial tile edge
constexpr int CCH  = 8;              // channels per LDS chunk
constexpr int NCH  = Cn / CCH;       // 32 chunks
constexpr int HALO = 4;
constexpr int X2R  = TILE + 2 * HALO;   // 24 staged rows
constexpr int X2C  = TILE + 2 * HALO;   // 24 staged cols
constexpr int X2S  = 28;                // padded row stride (floats): (7h+m)%8 granules balanced
constexpr int X2CH = X2R * X2S;         // 672 floats per channel
constexpr int NOFF = 81;

// Block: 576 threads = 9 waves. Wave w handles window row di = w (9 dj offsets).
// Each lane owns 4 consecutive x-pixels of a 16x16 tile.
// Per channel per lane: 1 global float4 (x1) + 3 ds_read_b128 (one x2 row window) + 36 FMA.

__global__ __launch_bounds__(576, 1)
void costvol_kernel(const float* __restrict__ x1,
                    const float* __restrict__ x2,
                    float* __restrict__ out)
{
  __shared__ float s2[2][CCH * X2CH];   // 43,008 B

  const int t    = threadIdx.x;
  const int wv   = t >> 6;             // 0..8 = di
  const int lane = t & 63;
  const int h    = lane >> 2;          // tile row 0..15
  const int m    = lane & 3;           // pixel group: cols 4m..4m+3

  const int tx = blockIdx.x, ty = blockIdx.y, b = blockIdx.z;
  const int x0 = tx * TILE, y0 = ty * TILE;

  // ---- x1: direct global, this thread's 4 pixels, per-channel stride HW ----
  const float* g1 = x1 + ((size_t)(b * Cn) * Hh + (y0 + h)) * Ww + (x0 + 4 * m);

  // ---- x2 staging map: 8 groups of 72 threads; group stages one channel ----
  // thread (group g=t/72, r=t%72) stages elements e = r + 72*j, j=0..7 of the
  // 24x24 tile: row = r/24 + 3j, col = r%24  (col constant per thread).
  const int   g    = t / 72;
  const int   r    = t % 72;
  const int   rrow = r / 24;
  const int   rcol = r % 24;
  const float* g2  = x2 + (size_t)(b * Cn) * HW + (size_t)g * HW;

  const int  gx   = x0 - HALO + rcol;
  const bool gxok = ((unsigned)gx < (unsigned)Ww);
  int  off[8];
  bool val[8];
#pragma unroll
  for (int j = 0; j < 8; ++j) {
    const int gy = y0 - HALO + rrow + 3 * j;
    const bool ok = gxok && ((unsigned)gy < (unsigned)Hh);
    val[j] = ok;
    off[j] = ok ? (gy * Ww + gx) : 0;
  }
  const int lbase = g * X2CH + rrow * X2S + rcol;   // + j*3*X2S per element

  float rs[8];
  auto stage_load = [&](int k) {
    const size_t cb = (size_t)(k * CCH) * HW;
#pragma unroll
    for (int j = 0; j < 8; ++j)
      rs[j] = val[j] ? g2[cb + off[j]] : 0.0f;
  };
  auto stage_write = [&](int nb) {
    float* s = s2[nb];
#pragma unroll
    for (int j = 0; j < 8; ++j)
      s[lbase + j * 3 * X2S] = rs[j];
  };

  float acc[9][4];
#pragma unroll
  for (int d = 0; d < 9; ++d)
#pragma unroll
    for (int p = 0; p < 4; ++p) acc[d][p] = 0.0f;

  // LDS read base for this lane's window row: row (h+wv), cols 4m..4m+11
  const int rbase = (h + wv) * X2S + 4 * m;

  stage_load(0);
  stage_write(0);
  __syncthreads();

  for (int k = 0; k < NCH; ++k) {
    if (k + 1 < NCH) stage_load(k + 1);            // issue early (T14)
    const float* sc = s2[k & 1];
#pragma unroll
    for (int cc = 0; cc < CCH; ++cc) {
      const float4 a = *reinterpret_cast<const float4*>(
          g1 + (size_t)(k * CCH + cc) * HW);
      const float* bp = sc + cc * X2CH + rbase;
      float w[12];
      *reinterpret_cast<float4*>(w)     = *reinterpret_cast<const float4*>(bp);
      *reinterpret_cast<float4*>(w + 4) = *reinterpret_cast<const float4*>(bp + 4);
      *reinterpret_cast<float4*>(w + 8) = *reinterpret_cast<const float4*>(bp + 8);
#pragma unroll
      for (int dj = 0; dj < 9; ++dj) {
        acc[dj][0] = fmaf(a.x, w[dj + 0], acc[dj][0]);
        acc[dj][1] = fmaf(a.y, w[dj + 1], acc[dj][1]);
        acc[dj][2] = fmaf(a.z, w[dj + 2], acc[dj][2]);
        acc[dj][3] = fmaf(a.w, w[dj + 3], acc[dj][3]);
      }
    }
    if (k + 1 < NCH) stage_write((k + 1) & 1);     // write late
    __syncthreads();
  }

  // ---- epilogue: o = 9*di + dj; each (b,o,y,x) written exactly once ----
  const float invc = 1.0f / (float)Cn;
  const int y  = y0 + h;
  const int xb = x0 + 4 * m;
#pragma unroll
  for (int dj = 0; dj < 9; ++dj) {
    const int o = wv * 9 + dj;
    float4 v;
    v.x = acc[dj][0] * invc;
    v.y = acc[dj][1] * invc;
    v.z = acc[dj][2] * invc;
    v.w = acc[dj][3] * invc;
    *reinterpret_cast<float4*>(out + (((size_t)b * NOFF + o) * Hh + y) * Ww + xb) = v;
  }
}

} // namespace

extern "C" void kernel_launch(void* const* d_in, const int* in_sizes, int n_in,
                              void* d_out, int out_size, void* d_ws, size_t ws_size,
                              hipStream_t stream) {
  const float* x1 = (const float*)d_in[0];
  const float* x2 = (const float*)d_in[1];
  float* out = (float*)d_out;

  dim3 grid(Ww / TILE, Hh / TILE, 4);   // 8 x 8 x 4 = 256 blocks
  dim3 block(576);                      // 9 waves: wave w <-> window row di=w
  costvol_kernel<<<grid, block, 0, stream>>>(x1, x2, out);
}